// Round 9
// baseline (1050.960 us; speedup 1.0000x reference)
//
#include <hip/hip_runtime.h>
#include <hip/hip_bf16.h>
#include <stdint.h>

// KGTN round 9.
// - Row-major XCD chunking restored everywhere (R8's col-major made each XCD
//   stream the full A panel on the final GEMM: FETCH 71->133 MB).
// - Split-K x2 (MFR=4) for avn and zr kept, but the reduction is fused into
//   the GEMM epilogue: all blocks write fp32 partials; threadfence + one
//   atomicAdd per block; last block (old==1) acquires, sums partner+own in
//   fixed zK order (2-operand fp add is commutative -> deterministic), applies
//   epilogue (avn: bf16 store; zr: sigmoid -> zv / rn_bf), resets counter.
//   Removes avn_sum/gates_sum and their ~70 MB/step round trip.
// - Counters zeroed via hipMemsetAsync each call (poison-safe, capture-legal).
// - Prep fused: 11 -> 6 launches.

typedef __attribute__((ext_vector_type(8))) short bf16x8;
typedef __attribute__((ext_vector_type(4))) float f32x4;
typedef __attribute__((ext_vector_type(4))) ushort u16x4;

typedef __attribute__((address_space(3))) void lds_void;
typedef const __attribute__((address_space(1))) void gbl_void;

__device__ __forceinline__ ushort f2b(float v) {
    union { float f; uint32_t u; } c; c.f = v;
    uint32_t u = c.u + 0x7FFFu + ((c.u >> 16) & 1u);   // RNE; inputs finite
    return (ushort)(u >> 16);
}

// Tile: BM=MFR*32 x BN=128, BK=64. A row-major bf16, Bt=B^T row-major bf16.
// Grid: x=N/128, y=M/BM, z = zA*zdiv + zK (zdiv = K-split factor).
// A = A[zA] + zK*aKoff, B = Bt + zA*bKa + zK*bKk.
// EPI 0: plain fp32 C at Cv + z*cOff.
// EPI 1: split-K x2 fused avn epilogue: partial at Cv + z*cOff; winner writes
//        bf16(p0+p1) to bfout[r*3072 + zA*1024 + c].
// EPI 2: split-K x2 fused gates: winner s=sigmoid(p0+p1); c<1024 -> zvp fp32;
//        else bfout[r*1024+c-1024] = bf16(s*nodes).
// Requires (gx*gy)%8==0, K%64==0, K/64>=2.
template <int MFR, int EPI>
__global__ __launch_bounds__(256) void gemm_t(
    const ushort* __restrict__ A0, const ushort* __restrict__ A1,
    const ushort* __restrict__ A2, const ushort* __restrict__ Bt,
    float* __restrict__ Cv, int K, long lda01, long lda2, long ldb, long ldc,
    long aKoff, long bKa, long bKk, long cOff, int zdiv,
    int* __restrict__ counters, float* __restrict__ zvp,
    ushort* __restrict__ bfout, const float* __restrict__ nodesp)
{
    __shared__ ushort As[2 * MFR * 2048];   // 2 x BM x 64
    __shared__ ushort Bs[2 * 8192];         // 2 x 128 x 64
    const int tid  = threadIdx.x;
    const int lane = tid & 63;
    const int wave = tid >> 6;
    const int wr = (wave >> 1) * (MFR * 16);   // wave row band
    const int wc = (wave & 1) * 64;            // wave col band

    // T1 row-major: XCD k owns a contiguous chunk of row-major bids.
    const int gx  = gridDim.x;
    const int nwg = gx * gridDim.y;
    int h0 = blockIdx.y * gx + blockIdx.x;
    const int bid = (h0 & 7) * (nwg >> 3) + (h0 >> 3);
    const long bm = (long)(bid / gx) * (MFR * 32);
    const long bn = (long)(bid % gx) * 128;

    const int z  = blockIdx.z;
    const int zA = z / zdiv;
    const int zK = z - zA * zdiv;
    const ushort* A  = ((zA == 0) ? A0 : (zA == 1) ? A1 : A2) + (long)zK * aKoff;
    const long lda   = (zA == 2) ? lda2 : lda01;
    const ushort* Bp = Bt + (long)zA * bKa + (long)zK * bKk;

    const int l15  = lane & 15;
    const int kg   = lane >> 4;                    // 0..3
    const int srow = lane >> 3;                    // 0..7
    const int gsw  = ((lane & 7) ^ srow) & 7;      // pre-swizzled src granule

    f32x4 acc[MFR][4] = {};

    auto STAGE = [&](int k0, int buf) {
        #pragma unroll
        for (int p = 0; p < MFR; ++p) {
            const int slot = wave * MFR + p;       // BM/8 slots x 8 rows
            const int row  = slot * 8 + srow;
            const ushort* ga = A + (bm + row) * lda + (k0 + gsw * 8);
            __builtin_amdgcn_global_load_lds((gbl_void*)ga,
                (lds_void*)(As + buf * MFR * 2048 + slot * 512), 16, 0, 0);
        }
        #pragma unroll
        for (int p = 0; p < 4; ++p) {
            const int slot = wave * 4 + p;         // 16 slots x 8 rows = 128
            const int row  = slot * 8 + srow;
            const ushort* gb = Bp + (bn + row) * ldb + (k0 + gsw * 8);
            __builtin_amdgcn_global_load_lds((gbl_void*)gb,
                (lds_void*)(Bs + buf * 8192 + slot * 512), 16, 0, 0);
        }
    };

    auto COMPUTE = [&](int buf) {
        const ushort* as = As + buf * MFR * 2048;
        const ushort* bs = Bs + buf * 8192;
        #pragma unroll
        for (int kk = 0; kk < 2; ++kk) {
            const int ph = (((kk * 4 + kg) ^ (lane & 7)) & 7) * 8;
            bf16x8 af[MFR], bv[4];
            #pragma unroll
            for (int m = 0; m < MFR; ++m)
                af[m] = *(const bf16x8*)(as + (wr + m * 16 + l15) * 64 + ph);
            #pragma unroll
            for (int n = 0; n < 4; ++n)
                bv[n] = *(const bf16x8*)(bs + (wc + n * 16 + l15) * 64 + ph);
            __builtin_amdgcn_s_setprio(1);
            #pragma unroll
            for (int m = 0; m < MFR; ++m)
                #pragma unroll
                for (int n = 0; n < 4; ++n)
                    acc[m][n] = __builtin_amdgcn_mfma_f32_16x16x32_bf16(
                        af[m], bv[n], acc[m][n], 0, 0, 0);
            __builtin_amdgcn_s_setprio(0);
        }
    };

#define SYNC()                                              \
    __builtin_amdgcn_sched_barrier(0);                      \
    asm volatile("s_waitcnt vmcnt(0)" ::: "memory");        \
    __builtin_amdgcn_s_barrier();                           \
    __builtin_amdgcn_sched_barrier(0)

    const int T = K >> 6;
    STAGE(0, 0);
    for (int t = 0; t < T; ++t) {
        SYNC();                            // tile t landed; compute t-1 done
        if (t + 1 < T) STAGE((t + 1) * 64, (t + 1) & 1);
        COMPUTE(t & 1);
    }
#undef SYNC

    // C/D layout: col = lane&15, row = (lane>>4)*4 + reg   [m89-verified]
    const int cr0 = (lane >> 4) * 4;
    float* P = Cv + cOff * z;
    #pragma unroll
    for (int m = 0; m < MFR; ++m) {
        #pragma unroll
        for (int j = 0; j < 4; ++j) {
            const long r = bm + wr + m * 16 + cr0 + j;
            #pragma unroll
            for (int n = 0; n < 4; ++n)
                P[r * ldc + bn + wc + n * 16 + l15] = acc[m][n][j];
        }
    }

    if (EPI != 0) {
        // split-K x2 fused reduction: last block per tile reduces + epilogue.
        __threadfence();                   // release own partial (agent scope)
        __shared__ int sflag;
        __syncthreads();
        const int cidx = zA * nwg + bid;
        if (tid == 0) sflag = atomicAdd(&counters[cidx], 1);
        __syncthreads();
        if (sflag == 1) {
            __threadfence();               // acquire partner's partial
            if (tid == 0) counters[cidx] = 0;   // reset for next use
            const float* Po = Cv + cOff * (z ^ 1);   // z^1 flips zK (zdiv=2)
            #pragma unroll
            for (int m = 0; m < MFR; ++m) {
                #pragma unroll
                for (int j = 0; j < 4; ++j) {
                    const long r = bm + wr + m * 16 + cr0 + j;
                    #pragma unroll
                    for (int n = 0; n < 4; ++n) {
                        const long c = bn + wc + n * 16 + l15;
                        const float other = Po[r * ldc + c];
                        const float mine  = acc[m][n][j];
                        const float a0 = (zK == 0) ? mine : other;
                        const float a1 = (zK == 0) ? other : mine;
                        const float v = a0 + a1;   // fixed zK order
                        if (EPI == 1) {
                            bfout[r * 3072 + (long)zA * 1024 + c] = f2b(v);
                        } else {
                            const float s = 1.f / (1.f + __expf(-v));
                            if (c < 1024) zvp[r * 1024 + c] = s;
                            else {
                                const long cc = c - 1024;
                                bfout[r * 1024 + cc] =
                                    f2b(s * nodesp[r * 1024 + cc]);
                            }
                        }
                    }
                }
            }
        }
    }
}

// fp32 -> bf16 elementwise, 4 elems/thread. n4 = total/4.
__global__ __launch_bounds__(256) void cvt_bf16_k(const float* __restrict__ src,
                                                  ushort* __restrict__ dst, long n4) {
    long i = (long)blockIdx.x * 256 + threadIdx.x;
    if (i >= n4) return;
    f32x4 v = *(const f32x4*)(src + i * 4);
    u16x4 o;
    #pragma unroll
    for (int j = 0; j < 4; ++j) o[j] = f2b(v[j]);
    *(u16x4*)(dst + i * 4) = o;
}

// inM [2048,2048]: straight bf16 copy + transposed bf16 in one read pass.
__global__ __launch_bounds__(256) void inM_dual_k(const float* __restrict__ src,
        ushort* __restrict__ dst, ushort* __restrict__ dstT) {
    __shared__ float t[32][33];
    const int c0 = blockIdx.x * 32, r0 = blockIdx.y * 32;
    const int tx = threadIdx.x & 31, ty = threadIdx.x >> 5;
    #pragma unroll
    for (int i = 0; i < 32; i += 8) {
        const float v = src[(long)(r0 + ty + i) * 2048 + c0 + tx];
        dst[(long)(r0 + ty + i) * 2048 + c0 + tx] = f2b(v);
        t[ty + i][tx] = v;
    }
    __syncthreads();
    #pragma unroll
    for (int i = 0; i < 32; i += 8)
        dstT[(long)(c0 + ty + i) * 2048 + r0 + tx] = f2b(t[tx][ty + i]);
}

// Three [2048,1024] W matrices -> transposed bf16 at dld=3072. z picks matrix.
__global__ __launch_bounds__(256) void wt3_k(const float* __restrict__ w3,
        const float* __restrict__ w4, const float* __restrict__ w5,
        ushort* __restrict__ Wzr, ushort* __restrict__ W5t) {
    __shared__ float t[32][33];
    const int zz = blockIdx.z;
    const float* src = (zz == 0) ? w3 : (zz == 1) ? w4 : w5;
    ushort* dst = (zz == 0) ? Wzr : (zz == 1) ? (Wzr + 3145728l) : W5t;
    const int c0 = blockIdx.x * 32, r0 = blockIdx.y * 32;
    const int tx = threadIdx.x & 31, ty = threadIdx.x >> 5;
    #pragma unroll
    for (int i = 0; i < 32; i += 8)
        t[ty + i][tx] = src[(long)(r0 + ty + i) * 1024 + c0 + tx];
    __syncthreads();
    #pragma unroll
    for (int i = 0; i < 32; i += 8)
        dst[(long)(c0 + ty + i) * 3072 + r0 + tx] = f2b(t[tx][ty + i]);
}

// Three [1024,1024] U matrices -> transposed bf16 at dld=3072, col offset 2048.
__global__ __launch_bounds__(256) void ut3_k(const float* __restrict__ u3,
        const float* __restrict__ u4, const float* __restrict__ u5,
        ushort* __restrict__ Wzr, ushort* __restrict__ W5t) {
    __shared__ float t[32][33];
    const int zz = blockIdx.z;
    const float* src = (zz == 0) ? u3 : (zz == 1) ? u4 : u5;
    ushort* dst = ((zz == 0) ? Wzr : (zz == 1) ? (Wzr + 3145728l) : W5t) + 2048;
    const int c0 = blockIdx.x * 32, r0 = blockIdx.y * 32;
    const int tx = threadIdx.x & 31, ty = threadIdx.x >> 5;
    #pragma unroll
    for (int i = 0; i < 32; i += 8)
        t[ty + i][tx] = src[(long)(r0 + ty + i) * 1024 + c0 + tx];
    __syncthreads();
    #pragma unroll
    for (int i = 0; i < 32; i += 8)
        dst[(long)(c0 + ty + i) * 3072 + r0 + tx] = f2b(t[tx][ty + i]);
}

// dst[c*dld + r] = bf16(src[r*C + c]). Grid (C/32, R/32), block 256.
__global__ __launch_bounds__(256) void transpose_cvt(const float* __restrict__ src,
                                                     ushort* __restrict__ dst,
                                                     int R, int C, int dld) {
    __shared__ float t[32][33];
    const int c0 = blockIdx.x * 32, r0 = blockIdx.y * 32;
    const int tx = threadIdx.x & 31, ty = threadIdx.x >> 5;
    #pragma unroll
    for (int i = 0; i < 32; i += 8)
        t[ty + i][tx] = src[(long)(r0 + ty + i) * C + c0 + tx];
    __syncthreads();
    #pragma unroll
    for (int i = 0; i < 32; i += 8)
        dst[(long)(c0 + ty + i) * dld + r0 + tx] = f2b(t[tx][ty + i]);
}

// From lfw [1024(h), 2048(N)]: nodesT_bf[h][N], nodes f32 [N][h],
// nodes_bf -> avn cols 2048:3072, init_bf -> ninit cols 1024:2048.
__global__ __launch_bounds__(256) void init_nodes_k(const float* __restrict__ lfw,
        ushort* __restrict__ nodesT, float* __restrict__ nodes,
        ushort* __restrict__ avn, ushort* __restrict__ ninit) {
    __shared__ float t[32][33];
    const int n0 = blockIdx.x * 32, h0 = blockIdx.y * 32;
    const int tx = threadIdx.x & 31, ty = threadIdx.x >> 5;
    #pragma unroll
    for (int i = 0; i < 32; i += 8) {
        float v = lfw[(long)(h0 + ty + i) * 2048 + n0 + tx];
        nodesT[(long)(h0 + ty + i) * 2048 + n0 + tx] = f2b(v);
        t[ty + i][tx] = v;
    }
    __syncthreads();
    #pragma unroll
    for (int i = 0; i < 32; i += 8) {
        const int n = n0 + ty + i, hh = h0 + tx;
        float v = t[tx][ty + i];
        nodes[(long)n * 1024 + hh] = v;
        ushort b = f2b(v);
        avn[(long)n * 3072 + 2048 + hh] = b;
        ninit[(long)n * 2048 + 1024 + hh] = b;
    }
}

// nodes = (1-z)*nodes + z*tanh(hp0+hp1+hp2); emit nodes_bf + transposed copy.
__global__ __launch_bounds__(256) void update_nodes_k(float* __restrict__ nodes,
        const float* __restrict__ zv, const float* __restrict__ hp,
        ushort* __restrict__ avn, ushort* __restrict__ ninit,
        ushort* __restrict__ nodesT) {
    __shared__ float t[32][33];
    const int c0 = blockIdx.x * 32, r0 = blockIdx.y * 32;
    const int tx = threadIdx.x & 31, ty = threadIdx.x >> 5;
    #pragma unroll
    for (int i = 0; i < 32; i += 8) {
        const int r = r0 + ty + i, c = c0 + tx;
        const long idx = (long)r * 1024 + c;
        const float z = zv[idx];
        const float hsum = hp[idx] + hp[idx + 2097152] + hp[idx + 4194304];
        const float nn = (1.f - z) * nodes[idx] + z * tanhf(hsum);
        nodes[idx] = nn;
        const ushort b = f2b(nn);
        avn[(long)r * 3072 + 2048 + c] = b;
        ninit[(long)r * 2048 + c] = b;
        t[ty + i][tx] = nn;
    }
    __syncthreads();
    #pragma unroll
    for (int i = 0; i < 32; i += 8)
        nodesT[(long)(c0 + ty + i) * 2048 + r0 + tx] = f2b(t[tx][ty + i]);
}

// v = sop0+sop1+bias; so_bf = bf16(v); partial sums of v^2. 1024 blocks.
__global__ __launch_bounds__(256) void bias_l2(const float* __restrict__ s,
        const float* __restrict__ bias, ushort* __restrict__ so_bf,
        float* __restrict__ partials) {
    __shared__ float red[256];
    const int tid = threadIdx.x;
    const long base = (long)blockIdx.x * 2048;
    float sum = 0.f;
    #pragma unroll
    for (int it = 0; it < 8; ++it) {
        const long i = base + tid + it * 256;
        const float v = s[i] + s[i + 2097152] + bias[i & 1023];
        so_bf[i] = f2b(v);
        sum += v * v;
    }
    red[tid] = sum;
    __syncthreads();
    #pragma unroll
    for (int w = 128; w > 0; w >>= 1) {
        if (tid < w) red[tid] += red[tid + w];
        __syncthreads();
    }
    if (tid == 0) partials[blockIdx.x] = red[0];
}

__global__ __launch_bounds__(256) void reduce_final(const float* __restrict__ partials,
                                                    float* __restrict__ out) {
    __shared__ float red[256];
    const int tid = threadIdx.x;
    red[tid] = partials[tid] + partials[tid + 256] + partials[tid + 512] + partials[tid + 768];
    __syncthreads();
    #pragma unroll
    for (int w = 128; w > 0; w >>= 1) {
        if (tid < w) red[tid] += red[tid + w];
        __syncthreads();
    }
    if (tid == 0) out[0] = red[0];
}

extern "C" void kernel_launch(void* const* d_in, const int* in_sizes, int n_in,
                              void* d_out, int out_size, void* d_ws, size_t ws_size,
                              hipStream_t stream) {
    const float* x   = (const float*)d_in[0];   // [8192,1024]
    const float* lfw = (const float*)d_in[1];   // [1024,2048]
    const float* inM = (const float*)d_in[2];   // [2048,2048]
    const float* w3w = (const float*)d_in[3];
    const float* w3u = (const float*)d_in[4];
    const float* w4w = (const float*)d_in[5];
    const float* w4u = (const float*)d_in[6];
    const float* w5w = (const float*)d_in[7];
    const float* w5u = (const float*)d_in[8];
    const float* fcw = (const float*)d_in[9];
    const float* fcb = (const float*)d_in[10];
    float* out = (float*)d_out;

    const int B = 8192, N = 2048;
    const long NH = 2097152;

    // d_out front as transient fp32 scratch (each region dead before next use;
    // all dead before the final GEMM rewrites d_out):
    float* avnp = out;                  // 4x [2048,1024] partials (32MB)
    float* zrp  = out;                  // 2x [2048,2048] partials (32MB)
    float* hpre = out;                  // 3x [2048,1024] partials (24MB)
    float* sop  = out;                  // 2x [2048,1024] partials (16MB)

    char* p = (char*)d_ws;
    auto alloc = [&](size_t bytes) {
        char* r = p; p += (bytes + 255) & ~(size_t)255; return r;
    };
    float*  nodes    = (float*)alloc(NH * 4);
    float*  zv       = (float*)alloc(NH * 4);
    float*  partials = (float*)alloc(1024 * 4);
    int*    counters = (int*)alloc(1024 * 4);
    ushort* avn      = (ushort*)alloc(6291456ull * 2);  // [2048,3072]
    ushort* rn_bf    = (ushort*)alloc(NH * 2);          // [2048,1024]
    ushort* nodesT   = (ushort*)alloc(NH * 2);          // [1024,2048]
    ushort* ninit    = (ushort*)alloc(4194304ull * 2);  // [2048,2048]
    ushort* inM_bf   = (ushort*)alloc(4194304ull * 2);
    ushort* inMT_bf  = (ushort*)alloc(4194304ull * 2);
    ushort* Wzr_t    = (ushort*)alloc(6291456ull * 2);  // [2048,3072]
    ushort* W5_t     = (ushort*)alloc(3145728ull * 2);  // [1024,3072]
    ushort* fcw_t    = (ushort*)alloc(NH * 2);          // [1024,2048]
    ushort* x_bf     = (ushort*)alloc(8388608ull * 2);  // [8192,1024]
    ushort* so_bf    = (ushort*)alloc(NH * 2);          // [2048,1024]

    const dim3 tb(256);

    // counters must be zero every call (ws is poisoned once before timing)
    hipMemsetAsync(counters, 0, 1024 * 4, stream);

    // ---- prep (6 launches) ----
    cvt_bf16_k<<<8192, tb, 0, stream>>>(x, x_bf, 2097152);
    inM_dual_k<<<dim3(64, 64), tb, 0, stream>>>(inM, inM_bf, inMT_bf);
    wt3_k<<<dim3(32, 64, 3), tb, 0, stream>>>(w3w, w4w, w5w, Wzr_t, W5_t);
    ut3_k<<<dim3(32, 32, 3), tb, 0, stream>>>(w3u, w4u, w5u, Wzr_t, W5_t);
    transpose_cvt<<<dim3(32, 64), tb, 0, stream>>>(fcw, fcw_t, 2048, 1024, 2048);
    init_nodes_k<<<dim3(64, 32), tb, 0, stream>>>(lfw, nodesT, nodes, avn, ninit);

    // ---- GGNN time steps ----
    for (int t = 0; t < 3; ++t) {
        // avn: z = zA*2+zK, zA in {in,inT}, zK K-half; fused bf16 reduction
        gemm_t<4, 1><<<dim3(8, 16, 4), tb, 0, stream>>>(
            inM_bf, inMT_bf, nullptr, nodesT, avnp,
            1024, 2048, 0, 2048, 1024,
            /*aKoff*/1024, /*bKa*/0, /*bKk*/1024, /*cOff*/2097152, /*zdiv*/2,
            counters, nullptr, avn, nullptr);
        // zr: split-K x2 over K=3072; fused sigmoid -> zv / rn_bf
        gemm_t<4, 2><<<dim3(16, 16, 2), tb, 0, stream>>>(
            avn, nullptr, nullptr, Wzr_t, zrp,
            1536, 3072, 0, 3072, 2048,
            /*aKoff*/1536, /*bKa*/0, /*bKk*/1536, /*cOff*/4194304, /*zdiv*/2,
            counters, zv, rn_bf, nodes);
        // hpre partials: zA in {av-low, av-high, rn}, K=1024 each
        gemm_t<2, 0><<<dim3(8, 32, 3), tb, 0, stream>>>(
            avn, avn + 1024, rn_bf, W5_t, hpre,
            1024, 3072, 1024, 3072, 1024,
            /*aKoff*/0, /*bKa*/1024, /*bKk*/0, /*cOff*/2097152, /*zdiv*/1,
            nullptr, nullptr, nullptr, nullptr);
        update_nodes_k<<<dim3(32, 64), tb, 0, stream>>>(nodes, zv, hpre, avn, ninit, nodesT);
    }

    // step_out partials = [nodes|init] @ fc_out_w  (2 zA parts, summed in bias_l2)
    gemm_t<2, 0><<<dim3(8, 32, 2), tb, 0, stream>>>(
        ninit, ninit + 1024, nullptr, fcw_t, sop,
        1024, 2048, 0, 2048, 1024,
        /*aKoff*/0, /*bKa*/1024, /*bKk*/0, /*cOff*/2097152, /*zdiv*/1,
        nullptr, nullptr, nullptr, nullptr);
    bias_l2<<<1024, tb, 0, stream>>>(sop, fcb, so_bf, partials);
    reduce_final<<<1, tb, 0, stream>>>(partials, out + (long)B * N);
    // output = x @ step_out^T  (128x128 tile, 1024 blocks)
    gemm_t<4, 0><<<dim3(16, 64, 1), tb, 0, stream>>>(
        x_bf, nullptr, nullptr, so_bf, out,
        1024, 1024, 0, 1024, 2048,
        /*aKoff*/0, /*bKa*/0, /*bKk*/0, /*cOff*/0, /*zdiv*/1,
        nullptr, nullptr, nullptr, nullptr);
}

// Round 10
// 420.541 us; speedup vs baseline: 2.4991x; 2.4991x over previous
//
#include <hip/hip_runtime.h>
#include <hip/hip_bf16.h>
#include <stdint.h>

// KGTN round 10 = R8 with ROW-major XCD chunking restored (single change).
// R9 lesson (journal): in-kernel cross-block reduction via __threadfence()
// is catastrophic on MI355X (non-coherent per-XCD L2 -> fence = L2 writeback;
// 162us vs 50us). Cross-block dataflow must cross a kernel boundary.
// R8 lesson: col-major chunking streams the full A panel per XCD (A is the
// big operand in every GEMM here) -> row-major chunking everywhere.
// Kept from R8: split-K x2 MFR=4 zr/avn GEMMs + separate avn_sum/gates_sum.

typedef __attribute__((ext_vector_type(8))) short bf16x8;
typedef __attribute__((ext_vector_type(4))) float f32x4;
typedef __attribute__((ext_vector_type(4))) ushort u16x4;

typedef __attribute__((address_space(3))) void lds_void;
typedef const __attribute__((address_space(1))) void gbl_void;

__device__ __forceinline__ ushort f2b(float v) {
    union { float f; uint32_t u; } c; c.f = v;
    uint32_t u = c.u + 0x7FFFu + ((c.u >> 16) & 1u);   // RNE; inputs finite
    return (ushort)(u >> 16);
}

// Tile: BM=MFR*32 x BN=128, BK=64. A row-major bf16, Bt=B^T row-major bf16.
// Grid: x=N/128, y=M/BM, z = zA*zdiv + zK. C fp32 partial z at Cv + z*cOff.
// Requires (gx*gy) % 8 == 0, K % 64 == 0, K/64 >= 2.
template <int MFR>
__global__ __launch_bounds__(256) void gemm_t(
    const ushort* __restrict__ A0, const ushort* __restrict__ A1,
    const ushort* __restrict__ A2, const ushort* __restrict__ Bt,
    float* __restrict__ Cv, int K, long lda01, long lda2, long ldb, long ldc,
    long aKoff, long bKa, long bKk, long cOff, int zdiv)
{
    __shared__ ushort As[2 * MFR * 2048];   // 2 x BM x 64
    __shared__ ushort Bs[2 * 8192];         // 2 x 128 x 64
    const int tid  = threadIdx.x;
    const int lane = tid & 63;
    const int wave = tid >> 6;
    const int wr = (wave >> 1) * (MFR * 16);   // wave row band
    const int wc = (wave & 1) * 64;            // wave col band

    // T1 row-major: XCD k owns a contiguous chunk of row-major bids ->
    // A panel read once per XCD (A is the big operand in every GEMM here).
    const int gx  = gridDim.x;
    const int nwg = gx * gridDim.y;
    int h0 = blockIdx.y * gx + blockIdx.x;
    const int bid = (h0 & 7) * (nwg >> 3) + (h0 >> 3);
    const long bm = (long)(bid / gx) * (MFR * 32);
    const long bn = (long)(bid % gx) * 128;

    const int z  = blockIdx.z;
    const int zA = z / zdiv;
    const int zK = z - zA * zdiv;
    const ushort* A  = ((zA == 0) ? A0 : (zA == 1) ? A1 : A2) + (long)zK * aKoff;
    const long lda   = (zA == 2) ? lda2 : lda01;
    const ushort* Bp = Bt + (long)zA * bKa + (long)zK * bKk;

    const int l15  = lane & 15;
    const int kg   = lane >> 4;                    // 0..3
    const int srow = lane >> 3;                    // 0..7
    const int gsw  = ((lane & 7) ^ srow) & 7;      // pre-swizzled src granule

    f32x4 acc[MFR][4] = {};

    auto STAGE = [&](int k0, int buf) {
        #pragma unroll
        for (int p = 0; p < MFR; ++p) {
            const int slot = wave * MFR + p;       // BM/8 slots x 8 rows
            const int row  = slot * 8 + srow;
            const ushort* ga = A + (bm + row) * lda + (k0 + gsw * 8);
            __builtin_amdgcn_global_load_lds((gbl_void*)ga,
                (lds_void*)(As + buf * MFR * 2048 + slot * 512), 16, 0, 0);
        }
        #pragma unroll
        for (int p = 0; p < 4; ++p) {
            const int slot = wave * 4 + p;         // 16 slots x 8 rows = 128
            const int row  = slot * 8 + srow;
            const ushort* gb = Bp + (bn + row) * ldb + (k0 + gsw * 8);
            __builtin_amdgcn_global_load_lds((gbl_void*)gb,
                (lds_void*)(Bs + buf * 8192 + slot * 512), 16, 0, 0);
        }
    };

    auto COMPUTE = [&](int buf) {
        const ushort* as = As + buf * MFR * 2048;
        const ushort* bs = Bs + buf * 8192;
        #pragma unroll
        for (int kk = 0; kk < 2; ++kk) {
            const int ph = (((kk * 4 + kg) ^ (lane & 7)) & 7) * 8;
            bf16x8 af[MFR], bv[4];
            #pragma unroll
            for (int m = 0; m < MFR; ++m)
                af[m] = *(const bf16x8*)(as + (wr + m * 16 + l15) * 64 + ph);
            #pragma unroll
            for (int n = 0; n < 4; ++n)
                bv[n] = *(const bf16x8*)(bs + (wc + n * 16 + l15) * 64 + ph);
            __builtin_amdgcn_s_setprio(1);
            #pragma unroll
            for (int m = 0; m < MFR; ++m)
                #pragma unroll
                for (int n = 0; n < 4; ++n)
                    acc[m][n] = __builtin_amdgcn_mfma_f32_16x16x32_bf16(
                        af[m], bv[n], acc[m][n], 0, 0, 0);
            __builtin_amdgcn_s_setprio(0);
        }
    };

#define SYNC()                                              \
    __builtin_amdgcn_sched_barrier(0);                      \
    asm volatile("s_waitcnt vmcnt(0)" ::: "memory");        \
    __builtin_amdgcn_s_barrier();                           \
    __builtin_amdgcn_sched_barrier(0)

    const int T = K >> 6;
    STAGE(0, 0);
    for (int t = 0; t < T; ++t) {
        SYNC();                            // tile t landed; compute t-1 done
        if (t + 1 < T) STAGE((t + 1) * 64, (t + 1) & 1);
        COMPUTE(t & 1);
    }
#undef SYNC

    // C/D layout: col = lane&15, row = (lane>>4)*4 + reg   [m89-verified]
    const int cr0 = (lane >> 4) * 4;
    float* C = Cv + cOff * z;
    #pragma unroll
    for (int m = 0; m < MFR; ++m) {
        #pragma unroll
        for (int j = 0; j < 4; ++j) {
            const long r = bm + wr + m * 16 + cr0 + j;
            #pragma unroll
            for (int n = 0; n < 4; ++n)
                C[r * ldc + bn + wc + n * 16 + l15] = acc[m][n][j];
        }
    }
}

// avn[:,0:1024] = bf16(p0+p1); avn[:,1024:2048] = bf16(p2+p3). 2048 x 256.
__global__ __launch_bounds__(256) void avn_sum_k(const float* __restrict__ p,
                                                 ushort* __restrict__ avn) {
    const long i = (long)blockIdx.x * 256 + threadIdx.x;   // over [2048,256] quads
    const long r = i >> 8, c = (i & 255) << 2;
    const long base = r * 1024 + c;
    f32x4 a0 = *(const f32x4*)(p + base);
    f32x4 a1 = *(const f32x4*)(p + 2097152 + base);
    f32x4 b0 = *(const f32x4*)(p + 4194304 + base);
    f32x4 b1 = *(const f32x4*)(p + 6291456 + base);
    u16x4 oa, ob;
    #pragma unroll
    for (int j = 0; j < 4; ++j) {
        oa[j] = f2b(a0[j] + a1[j]);
        ob[j] = f2b(b0[j] + b1[j]);
    }
    *(u16x4*)(avn + r * 3072 + c) = oa;
    *(u16x4*)(avn + r * 3072 + 1024 + c) = ob;
}

// zv = sigmoid(zp0+zp1); rn_bf = bf16(sigmoid(rp0+rp1)*nodes). 2048 x 256.
__global__ __launch_bounds__(256) void gates_sum_k(const float* __restrict__ p,
        const float* __restrict__ nodes, float* __restrict__ zv,
        ushort* __restrict__ rn) {
    const long i = (long)blockIdx.x * 256 + threadIdx.x;
    const long r = i >> 8, c = (i & 255) << 2;
    const long base = r * 2048 + c;
    f32x4 z0 = *(const f32x4*)(p + base);
    f32x4 z1 = *(const f32x4*)(p + 4194304 + base);
    f32x4 r0 = *(const f32x4*)(p + base + 1024);
    f32x4 r1 = *(const f32x4*)(p + 4194304 + base + 1024);
    f32x4 nd = *(const f32x4*)(nodes + r * 1024 + c);
    f32x4 zo;
    u16x4 ro;
    #pragma unroll
    for (int j = 0; j < 4; ++j) {
        zo[j] = 1.f / (1.f + __expf(-(z0[j] + z1[j])));
        ro[j] = f2b(nd[j] / (1.f + __expf(-(r0[j] + r1[j]))));
    }
    *(f32x4*)(zv + r * 1024 + c) = zo;
    *(u16x4*)(rn + r * 1024 + c) = ro;
}

// fp32 -> bf16 elementwise, 4 elems/thread. n4 = total/4.
__global__ __launch_bounds__(256) void cvt_bf16_k(const float* __restrict__ src,
                                                  ushort* __restrict__ dst, long n4) {
    long i = (long)blockIdx.x * 256 + threadIdx.x;
    if (i >= n4) return;
    f32x4 v = *(const f32x4*)(src + i * 4);
    u16x4 o;
    #pragma unroll
    for (int j = 0; j < 4; ++j) o[j] = f2b(v[j]);
    *(u16x4*)(dst + i * 4) = o;
}

// inM [2048,2048]: straight bf16 copy + transposed bf16 in one read pass.
__global__ __launch_bounds__(256) void inM_dual_k(const float* __restrict__ src,
        ushort* __restrict__ dst, ushort* __restrict__ dstT) {
    __shared__ float t[32][33];
    const int c0 = blockIdx.x * 32, r0 = blockIdx.y * 32;
    const int tx = threadIdx.x & 31, ty = threadIdx.x >> 5;
    #pragma unroll
    for (int i = 0; i < 32; i += 8) {
        const float v = src[(long)(r0 + ty + i) * 2048 + c0 + tx];
        dst[(long)(r0 + ty + i) * 2048 + c0 + tx] = f2b(v);
        t[ty + i][tx] = v;
    }
    __syncthreads();
    #pragma unroll
    for (int i = 0; i < 32; i += 8)
        dstT[(long)(c0 + ty + i) * 2048 + r0 + tx] = f2b(t[tx][ty + i]);
}

// Three [2048,1024] W matrices -> transposed bf16 at dld=3072. z picks matrix.
__global__ __launch_bounds__(256) void wt3_k(const float* __restrict__ w3,
        const float* __restrict__ w4, const float* __restrict__ w5,
        ushort* __restrict__ Wzr, ushort* __restrict__ W5t) {
    __shared__ float t[32][33];
    const int zz = blockIdx.z;
    const float* src = (zz == 0) ? w3 : (zz == 1) ? w4 : w5;
    ushort* dst = (zz == 0) ? Wzr : (zz == 1) ? (Wzr + 3145728l) : W5t;
    const int c0 = blockIdx.x * 32, r0 = blockIdx.y * 32;
    const int tx = threadIdx.x & 31, ty = threadIdx.x >> 5;
    #pragma unroll
    for (int i = 0; i < 32; i += 8)
        t[ty + i][tx] = src[(long)(r0 + ty + i) * 1024 + c0 + tx];
    __syncthreads();
    #pragma unroll
    for (int i = 0; i < 32; i += 8)
        dst[(long)(c0 + ty + i) * 3072 + r0 + tx] = f2b(t[tx][ty + i]);
}

// Three [1024,1024] U matrices -> transposed bf16 at dld=3072, col offset 2048.
__global__ __launch_bounds__(256) void ut3_k(const float* __restrict__ u3,
        const float* __restrict__ u4, const float* __restrict__ u5,
        ushort* __restrict__ Wzr, ushort* __restrict__ W5t) {
    __shared__ float t[32][33];
    const int zz = blockIdx.z;
    const float* src = (zz == 0) ? u3 : (zz == 1) ? u4 : u5;
    ushort* dst = ((zz == 0) ? Wzr : (zz == 1) ? (Wzr + 3145728l) : W5t) + 2048;
    const int c0 = blockIdx.x * 32, r0 = blockIdx.y * 32;
    const int tx = threadIdx.x & 31, ty = threadIdx.x >> 5;
    #pragma unroll
    for (int i = 0; i < 32; i += 8)
        t[ty + i][tx] = src[(long)(r0 + ty + i) * 1024 + c0 + tx];
    __syncthreads();
    #pragma unroll
    for (int i = 0; i < 32; i += 8)
        dst[(long)(c0 + ty + i) * 3072 + r0 + tx] = f2b(t[tx][ty + i]);
}

// dst[c*dld + r] = bf16(src[r*C + c]). Grid (C/32, R/32), block 256.
__global__ __launch_bounds__(256) void transpose_cvt(const float* __restrict__ src,
                                                     ushort* __restrict__ dst,
                                                     int R, int C, int dld) {
    __shared__ float t[32][33];
    const int c0 = blockIdx.x * 32, r0 = blockIdx.y * 32;
    const int tx = threadIdx.x & 31, ty = threadIdx.x >> 5;
    #pragma unroll
    for (int i = 0; i < 32; i += 8)
        t[ty + i][tx] = src[(long)(r0 + ty + i) * C + c0 + tx];
    __syncthreads();
    #pragma unroll
    for (int i = 0; i < 32; i += 8)
        dst[(long)(c0 + ty + i) * dld + r0 + tx] = f2b(t[tx][ty + i]);
}

// From lfw [1024(h), 2048(N)]: nodesT_bf[h][N], nodes f32 [N][h],
// nodes_bf -> avn cols 2048:3072, init_bf -> ninit cols 1024:2048.
__global__ __launch_bounds__(256) void init_nodes_k(const float* __restrict__ lfw,
        ushort* __restrict__ nodesT, float* __restrict__ nodes,
        ushort* __restrict__ avn, ushort* __restrict__ ninit) {
    __shared__ float t[32][33];
    const int n0 = blockIdx.x * 32, h0 = blockIdx.y * 32;
    const int tx = threadIdx.x & 31, ty = threadIdx.x >> 5;
    #pragma unroll
    for (int i = 0; i < 32; i += 8) {
        float v = lfw[(long)(h0 + ty + i) * 2048 + n0 + tx];
        nodesT[(long)(h0 + ty + i) * 2048 + n0 + tx] = f2b(v);
        t[ty + i][tx] = v;
    }
    __syncthreads();
    #pragma unroll
    for (int i = 0; i < 32; i += 8) {
        const int n = n0 + ty + i, hh = h0 + tx;
        float v = t[tx][ty + i];
        nodes[(long)n * 1024 + hh] = v;
        ushort b = f2b(v);
        avn[(long)n * 3072 + 2048 + hh] = b;
        ninit[(long)n * 2048 + 1024 + hh] = b;
    }
}

// nodes = (1-z)*nodes + z*tanh(hp0+hp1+hp2); emit nodes_bf + transposed copy.
__global__ __launch_bounds__(256) void update_nodes_k(float* __restrict__ nodes,
        const float* __restrict__ zv, const float* __restrict__ hp,
        ushort* __restrict__ avn, ushort* __restrict__ ninit,
        ushort* __restrict__ nodesT) {
    __shared__ float t[32][33];
    const int c0 = blockIdx.x * 32, r0 = blockIdx.y * 32;
    const int tx = threadIdx.x & 31, ty = threadIdx.x >> 5;
    #pragma unroll
    for (int i = 0; i < 32; i += 8) {
        const int r = r0 + ty + i, c = c0 + tx;
        const long idx = (long)r * 1024 + c;
        const float z = zv[idx];
        const float hsum = hp[idx] + hp[idx + 2097152] + hp[idx + 4194304];
        const float nn = (1.f - z) * nodes[idx] + z * tanhf(hsum);
        nodes[idx] = nn;
        const ushort b = f2b(nn);
        avn[(long)r * 3072 + 2048 + c] = b;
        ninit[(long)r * 2048 + c] = b;
        t[ty + i][tx] = nn;
    }
    __syncthreads();
    #pragma unroll
    for (int i = 0; i < 32; i += 8)
        nodesT[(long)(c0 + ty + i) * 2048 + r0 + tx] = f2b(t[tx][ty + i]);
}

// v = sop0+sop1+bias; so_bf = bf16(v); partial sums of v^2. 1024 blocks.
__global__ __launch_bounds__(256) void bias_l2(const float* __restrict__ s,
        const float* __restrict__ bias, ushort* __restrict__ so_bf,
        float* __restrict__ partials) {
    __shared__ float red[256];
    const int tid = threadIdx.x;
    const long base = (long)blockIdx.x * 2048;
    float sum = 0.f;
    #pragma unroll
    for (int it = 0; it < 8; ++it) {
        const long i = base + tid + it * 256;
        const float v = s[i] + s[i + 2097152] + bias[i & 1023];
        so_bf[i] = f2b(v);
        sum += v * v;
    }
    red[tid] = sum;
    __syncthreads();
    #pragma unroll
    for (int w = 128; w > 0; w >>= 1) {
        if (tid < w) red[tid] += red[tid + w];
        __syncthreads();
    }
    if (tid == 0) partials[blockIdx.x] = red[0];
}

__global__ __launch_bounds__(256) void reduce_final(const float* __restrict__ partials,
                                                    float* __restrict__ out) {
    __shared__ float red[256];
    const int tid = threadIdx.x;
    red[tid] = partials[tid] + partials[tid + 256] + partials[tid + 512] + partials[tid + 768];
    __syncthreads();
    #pragma unroll
    for (int w = 128; w > 0; w >>= 1) {
        if (tid < w) red[tid] += red[tid + w];
        __syncthreads();
    }
    if (tid == 0) out[0] = red[0];
}

extern "C" void kernel_launch(void* const* d_in, const int* in_sizes, int n_in,
                              void* d_out, int out_size, void* d_ws, size_t ws_size,
                              hipStream_t stream) {
    const float* x   = (const float*)d_in[0];   // [8192,1024]
    const float* lfw = (const float*)d_in[1];   // [1024,2048]
    const float* inM = (const float*)d_in[2];   // [2048,2048]
    const float* w3w = (const float*)d_in[3];
    const float* w3u = (const float*)d_in[4];
    const float* w4w = (const float*)d_in[5];
    const float* w4u = (const float*)d_in[6];
    const float* w5w = (const float*)d_in[7];
    const float* w5u = (const float*)d_in[8];
    const float* fcw = (const float*)d_in[9];
    const float* fcb = (const float*)d_in[10];
    float* out = (float*)d_out;

    const int B = 8192, N = 2048;
    const long NH = 2097152;

    // d_out front as transient fp32 scratch (each region dead before next use;
    // all dead before the final GEMM rewrites d_out):
    float* avnp = out;                  // 4x [2048,1024] partials (32MB)
    float* zrp  = out;                  // 2x [2048,2048] partials (32MB)
    float* hpre = out;                  // 3x [2048,1024] partials (24MB)
    float* sop  = out;                  // 2x [2048,1024] partials (16MB)

    char* p = (char*)d_ws;
    auto alloc = [&](size_t bytes) {
        char* r = p; p += (bytes + 255) & ~(size_t)255; return r;
    };
    float*  nodes    = (float*)alloc(NH * 4);
    float*  zv       = (float*)alloc(NH * 4);
    float*  partials = (float*)alloc(1024 * 4);
    ushort* avn      = (ushort*)alloc(6291456ull * 2);  // [2048,3072]
    ushort* rn_bf    = (ushort*)alloc(NH * 2);          // [2048,1024]
    ushort* nodesT   = (ushort*)alloc(NH * 2);          // [1024,2048]
    ushort* ninit    = (ushort*)alloc(4194304ull * 2);  // [2048,2048]
    ushort* inM_bf   = (ushort*)alloc(4194304ull * 2);
    ushort* inMT_bf  = (ushort*)alloc(4194304ull * 2);
    ushort* Wzr_t    = (ushort*)alloc(6291456ull * 2);  // [2048,3072]
    ushort* W5_t     = (ushort*)alloc(3145728ull * 2);  // [1024,3072]
    ushort* fcw_t    = (ushort*)alloc(NH * 2);          // [1024,2048]
    ushort* x_bf     = (ushort*)alloc(8388608ull * 2);  // [8192,1024]
    ushort* so_bf    = (ushort*)alloc(NH * 2);          // [2048,1024]

    const dim3 tb(256);

    // ---- prep (6 launches) ----
    cvt_bf16_k<<<8192, tb, 0, stream>>>(x, x_bf, 2097152);
    inM_dual_k<<<dim3(64, 64), tb, 0, stream>>>(inM, inM_bf, inMT_bf);
    wt3_k<<<dim3(32, 64, 3), tb, 0, stream>>>(w3w, w4w, w5w, Wzr_t, W5_t);
    ut3_k<<<dim3(32, 32, 3), tb, 0, stream>>>(w3u, w4u, w5u, Wzr_t, W5_t);
    transpose_cvt<<<dim3(32, 64), tb, 0, stream>>>(fcw, fcw_t, 2048, 1024, 2048);
    init_nodes_k<<<dim3(64, 32), tb, 0, stream>>>(lfw, nodesT, nodes, avn, ninit);

    // ---- GGNN time steps ----
    for (int t = 0; t < 3; ++t) {
        // avn partials: z = zA*2+zK, zA in {in,inT}, zK = K-half of 2048
        gemm_t<4><<<dim3(8, 16, 4), tb, 0, stream>>>(
            inM_bf, inMT_bf, nullptr, nodesT, avnp,
            1024, 2048, 0, 2048, 1024,
            /*aKoff*/1024, /*bKa*/0, /*bKk*/1024, /*cOff*/2097152, /*zdiv*/2);
        avn_sum_k<<<2048, tb, 0, stream>>>(avnp, avn);
        // zr partials: split-K x2 over K=3072
        gemm_t<4><<<dim3(16, 16, 2), tb, 0, stream>>>(
            avn, nullptr, nullptr, Wzr_t, zrp,
            1536, 3072, 0, 3072, 2048,
            /*aKoff*/1536, /*bKa*/0, /*bKk*/1536, /*cOff*/4194304, /*zdiv*/2);
        gates_sum_k<<<2048, tb, 0, stream>>>(zrp, nodes, zv, rn_bf);
        // hpre partials: zA in {av-low, av-high, rn}, K=1024 each
        gemm_t<2><<<dim3(8, 32, 3), tb, 0, stream>>>(
            avn, avn + 1024, rn_bf, W5_t, hpre,
            1024, 3072, 1024, 3072, 1024,
            /*aKoff*/0, /*bKa*/1024, /*bKk*/0, /*cOff*/2097152, /*zdiv*/1);
        update_nodes_k<<<dim3(32, 64), tb, 0, stream>>>(nodes, zv, hpre, avn, ninit, nodesT);
    }

    // step_out partials = [nodes|init] @ fc_out_w  (split-K x2 via zA)
    gemm_t<2><<<dim3(8, 32, 2), tb, 0, stream>>>(
        ninit, ninit + 1024, nullptr, fcw_t, sop,
        1024, 2048, 0, 2048, 1024,
        /*aKoff*/0, /*bKa*/1024, /*bKk*/0, /*cOff*/2097152, /*zdiv*/1);
    bias_l2<<<1024, tb, 0, stream>>>(sop, fcb, so_bf, partials);
    reduce_final<<<1, tb, 0, stream>>>(partials, out + (long)B * N);
    // output = x @ step_out^T  (128x128 tile, 1024 blocks)
    gemm_t<4><<<dim3(16, 64, 1), tb, 0, stream>>>(
        x_bf, nullptr, nullptr, so_bf, out,
        1024, 1024, 0, 1024, 2048,
        /*aKoff*/0, /*bKa*/0, /*bKk*/0, /*cOff*/0, /*zdiv*/1);
}